// Round 11
// baseline (218.779 us; speedup 1.0000x reference)
//
#include <hip/hip_runtime.h>
#include <hip/hip_bf16.h>

#define B_    16
#define N_    4
#define COUT  256
#define CIN   256
#define H_    64
#define W_    64
#define K_TOT (CIN * 9)    // 2304, k = p*256 + cin (p-major)
#define HW    (H_ * W_)    // 4096
#define PAD   66
#define PLANE (PAD * PAD)  // 4356 padded pixels per (b, cb4) plane
#define SLABU 25344        // 6*66*64 ushorts per slab (49.5 KB)

typedef __attribute__((ext_vector_type(8))) short short8;
typedef __attribute__((ext_vector_type(4))) float f32x4;
typedef unsigned short ushort_t;

static __device__ __forceinline__ ushort_t f2bf(float f) {
    __hip_bfloat16 h = __float2bfloat16(f);
    return *reinterpret_cast<ushort_t*>(&h);
}

// ---------------------------------------------------------------------------
// Kernel 1: 9x9 rotation matrices, scaled by alpha.  rm[b*N_+n][9][9] floats.
// ---------------------------------------------------------------------------
__global__ void rot_mats_kernel(const float* __restrict__ alphas,
                                const float* __restrict__ angles,
                                float* __restrict__ rm) {
    int i = threadIdx.x;
    if (i >= B_ * N_) return;
    float th = angles[i], al = alphas[i];
    float xc = cosf(th), ys = sinf(th);
    float a = xc - ys, b = xc * ys, c = xc + ys;
    float r[81];
#pragma unroll
    for (int j = 0; j < 81; ++j) r[j] = 0.f;
    if (th >= 0.f) {
        r[0] = a;          r[1] = 1.f - a;
        r[10] = xc - b;    r[11] = b;        r[13] = 1.f - c + b; r[14] = ys - b;
        r[20] = a;         r[23] = 1.f - a;
        r[27] = b;         r[28] = ys - b;   r[30] = xc - b;      r[31] = 1.f - c + b;
        r[40] = 1.f;
        r[49] = 1.f - c + b; r[50] = xc - b; r[52] = ys - b;      r[53] = b;
        r[57] = 1.f - a;   r[60] = a;
        r[66] = ys - b;    r[67] = 1.f - c + b; r[69] = b;        r[70] = xc - b;
        r[79] = 1.f - a;   r[80] = a;
    } else {
        r[0] = c;          r[3] = 1.f - c;
        r[9] = -b;         r[10] = xc + b;   r[12] = b - ys;      r[13] = 1.f - a - b;
        r[19] = 1.f - c;   r[20] = c;
        r[30] = xc + b;    r[31] = 1.f - a - b; r[33] = -b;       r[34] = b - ys;
        r[40] = 1.f;
        r[46] = b - ys;    r[47] = -b;       r[49] = 1.f - a - b; r[50] = xc + b;
        r[60] = c;         r[61] = 1.f - c;
        r[67] = 1.f - a - b; r[68] = b - ys; r[70] = xc + b;      r[71] = -b;
        r[77] = 1.f - c;   r[80] = c;
    }
#pragma unroll
    for (int j = 0; j < 81; ++j) rm[i * 81 + j] = r[j] * al;
}

// ---------------------------------------------------------------------------
// Kernel 2: rw[b][cout][p*256 + cin] (bf16, p-major K layout)
// ---------------------------------------------------------------------------
__global__ __launch_bounds__(256)
void build_rw_kernel(const float* __restrict__ weight,
                     const float* __restrict__ rm,
                     ushort_t* __restrict__ rw) {
    __shared__ float rms[N_ * 81];        // 324 floats
    int tid = threadIdx.x;
    int b = blockIdx.y;
    for (int j = tid; j < N_ * 81; j += 256)
        rms[j] = rm[b * N_ * 81 + j];
    __syncthreads();

    int idx = blockIdx.x * 256 + tid;     // cout*256 + cin
    int cout = idx >> 8, cin = idx & 255;

    float wv[N_][9];
#pragma unroll
    for (int n = 0; n < N_; ++n)
#pragma unroll
        for (int q = 0; q < 9; ++q)
            wv[n][q] = weight[(size_t)(n * (COUT * CIN) + idx) * 9 + q];

    ushort_t* dst = rw + (size_t)(b * COUT + cout) * K_TOT + cin;
#pragma unroll
    for (int p = 0; p < 9; ++p) {
        float s = 0.f;
#pragma unroll
        for (int n = 0; n < N_; ++n)
#pragma unroll
            for (int q = 0; q < 9; ++q)
                s += rms[n * 81 + p * 9 + q] * wv[n][q];
        dst[p * 256] = f2bf(s);
    }
}

// ---------------------------------------------------------------------------
// Kernel 2a: zero the halo ring of each padded plane (260 px x 64 cin).
// grid: 64 planes (b*4 + cb4).
// ---------------------------------------------------------------------------
__global__ __launch_bounds__(256)
void halo_zero_kernel(ushort_t* __restrict__ xt) {
    ushort_t* base = xt + (size_t)blockIdx.x * PLANE * 64;
    int t = threadIdx.x;
    for (int i = t; i < 260; i += 256) {
        int py, px;
        if (i < 66)       { py = 0;  px = i; }
        else if (i < 132) { py = 65; px = i - 66; }
        else if (i < 196) { py = i - 132 + 1; px = 0; }
        else              { py = i - 196 + 1; px = 65; }
        ushort_t* d = base + (size_t)(py * PAD + px) * 64;
        int4 z = {0, 0, 0, 0};
#pragma unroll
        for (int q = 0; q < 8; ++q) *(int4*)(d + q * 8) = z;
    }
}

// ---------------------------------------------------------------------------
// Kernel 2b: interior repack: x fp32 [b][c][64][64] -> xt bf16
//   [b][cb4(4)][y+1][x+1][64cin].  grid (64 rows, 8 cb32, B_), 256 thr.
// ---------------------------------------------------------------------------
__global__ __launch_bounds__(256)
void nhwc_kernel(const float* __restrict__ x, ushort_t* __restrict__ xt) {
    int y    = blockIdx.x;
    int cb32 = blockIdx.y;
    int b    = blockIdx.z;
    __shared__ ushort_t tileT[64][40];    // [px][ci(32)], 80B rows
    int t = threadIdx.x;

    int ci = t & 31, seg = t >> 5;        // 8 segs x 8 px
    const float* src = x + ((size_t)(b * CIN + cb32 * 32 + ci) * HW + y * 64 + seg * 8);
    float4 f0 = ((const float4*)src)[0];
    float4 f1 = ((const float4*)src)[1];
#pragma unroll
    for (int q = 0; q < 4; ++q) tileT[seg * 8 + q][ci]     = f2bf(((float*)&f0)[q]);
#pragma unroll
    for (int q = 0; q < 4; ++q) tileT[seg * 8 + 4 + q][ci] = f2bf(((float*)&f1)[q]);
    __syncthreads();

    int px = t >> 2, cseg = t & 3;        // 64 px x 4 x 16B
    ushort_t* dst = xt + ((size_t)(b * 4 + (cb32 >> 1)) * PLANE + (y + 1) * PAD + px + 1) * 64
                       + (cb32 & 1) * 32 + cseg * 8;
    *(int4*)dst = *(const int4*)&tileT[px][cseg * 8];
}

// ---------------------------------------------------------------------------
// Kernel 3: barrier-free implicit-GEMM conv.
// Block = 256 couts x 256 px (4 image rows), 512 thr = 8 waves (2M x 4N),
// wave tile 128x64, acc[8][4].
// K-order: cb4 outer (4), tap p inner (9).
// B: 6x66x64 pixel slab resident in LDS for all 9 taps (dbuf, reg-staged
//    next slab 1 unit/tap, T14); slot swizzle seg^(r&7), 128B rows (proven
//    0-conflict in R8/R10), source pre-swizzled (rule #21).
// A: direct global->VGPR fragment loads (L2-resident rw; 64B coalesced segs,
//    one 128B line per row per K-tile, shared by wn-quad via L1).
// Sync: ONE __syncthreads per cb4 (slab switch) - 5 barriers total vs R8's 288.
// ---------------------------------------------------------------------------
__global__ __launch_bounds__(512, 2)
void conv_kernel(const ushort_t* __restrict__ xt,
                 const ushort_t* __restrict__ rw,
                 float* __restrict__ out) {
    int bid0 = blockIdx.x;
    int bid = (bid0 & 7) * 32 + (bid0 >> 3);   // 256 = 8*32: bijective
    int b    = bid >> 4;
    int tile = bid & 15;        // pixel tile: 4 image rows
    int y0 = tile * 4;
    int tid = threadIdx.x;
    int lane = tid & 63, wid = tid >> 6;
    int wm = wid >> 2, wn = wid & 3;
    int rA = lane & 15, kseg = lane >> 4;

    __shared__ __align__(16) ushort_t slab[2][SLABU];   // 2 x 49.5 KB

    f32x4 acc[8][4] = {};

    const ushort_t* rwb = rw + (size_t)b * COUT * K_TOT;
    const ushort_t* xtb = xt + (size_t)b * 4 * PLANE * 64;

    // A per-lane fragment base: row = wm*128 + mi*16 + rA, k-chunk = kseg*8
    const ushort_t* aBase = rwb + (size_t)(wm * 128 + rA) * K_TOT + kseg * 8;

    // B per-lane pixel base per ni: pidx = wn*64 + ni*16 + rA
    int bpix[4];
#pragma unroll
    for (int ni = 0; ni < 4; ++ni) {
        int pidx = wn * 64 + ni * 16 + rA;
        bpix[ni] = (pidx >> 6) * PAD + (pidx & 63);
    }

    // slab staging: 3168 units of 16B; unit u -> LDS offset u*8 (ushorts),
    // global src element offset = (u&~7)*8 + ((u&7)^((u>>3)&7))*8  (pre-swz)
#define SRC_OFF(U) ((((U) & ~7) + (((U) & 7) ^ (((U) >> 3) & 7))) * 8)
    const bool tail = tid < 96;

    // ---- prologue: stage slab for cb4=0 into buf 0 ----
    {
        const ushort_t* g = xtb + (size_t)y0 * PAD * 64;   // cb4=0 slab base
#pragma unroll
        for (int ps = 0; ps < 6; ++ps) {
            int u = ps * 512 + tid;
            short8 v = *(const short8*)(g + SRC_OFF(u));
            *(short8*)(&slab[0][u * 8]) = v;
        }
        if (tail) {
            int u = 3072 + tid;
            short8 v = *(const short8*)(g + SRC_OFF(u));
            *(short8*)(&slab[0][u * 8]) = v;
        }
    }
    __syncthreads();

    int buf = 0;
    for (int cb4 = 0; cb4 < 4; ++cb4) {
        const ushort_t* gnext = xtb + (size_t)((cb4 + 1) * PLANE + y0 * PAD) * 64;
        const ushort_t* ab4 = aBase + cb4 * 64;
        const ushort_t* sl = &slab[buf][0];
        ushort_t* sln = &slab[buf ^ 1][0];
        bool more = (cb4 < 3);

#pragma unroll
        for (int p = 0; p < 9; ++p) {
            const int ph = p / 3, pw = p - 3 * ph;
            // ---- stage-next slab: one unit this tap ----
            if (more) {
                if (p < 6) {
                    int u = p * 512 + tid;
                    short8 v = *(const short8*)(gnext + SRC_OFF(u));
                    *(short8*)(&sln[u * 8]) = v;
                } else if (p == 6 && tail) {
                    int u = 3072 + tid;
                    short8 v = *(const short8*)(gnext + SRC_OFF(u));
                    *(short8*)(&sln[u * 8]) = v;
                }
            }
            const ushort_t* ab = ab4 + p * 256;
#pragma unroll
            for (int kh = 0; kh < 2; ++kh) {
                // A fragments: 8 direct global b128
                short8 a[8];
#pragma unroll
                for (int mi = 0; mi < 8; ++mi)
                    a[mi] = *(const short8*)(ab + (size_t)mi * 16 * K_TOT + kh * 32);
                // B fragments: 4 ds_read_b128 from slab
                short8 bv[4];
#pragma unroll
                for (int ni = 0; ni < 4; ++ni) {
                    int rs = bpix[ni] + ph * PAD + pw;
                    bv[ni] = *(const short8*)(&sl[rs * 64
                              + ((((kh << 2) | kseg) ^ (rs & 7)) * 8)]);
                }
                // 32 MFMA
                __builtin_amdgcn_s_setprio(1);
#pragma unroll
                for (int mi = 0; mi < 8; ++mi)
#pragma unroll
                    for (int ni = 0; ni < 4; ++ni)
                        acc[mi][ni] = __builtin_amdgcn_mfma_f32_16x16x32_bf16(
                            a[mi], bv[ni], acc[mi][ni], 0, 0, 0);
                __builtin_amdgcn_s_setprio(0);
            }
        }
        __syncthreads();   // slab switch: next-slab writes visible, reads done
        buf ^= 1;
    }
#undef SRC_OFF

    // ---- epilogue: D[row=(lane>>4)*4+rr][col=lane&15] ----
    int row0 = (lane >> 4) * 4;
    int col  = lane & 15;
    float* outb = out + (size_t)b * COUT * HW + tile * 256;
#pragma unroll
    for (int am = 0; am < 8; ++am)
#pragma unroll
        for (int an = 0; an < 4; ++an)
#pragma unroll
            for (int rr = 0; rr < 4; ++rr) {
                int m = wm * 128 + am * 16 + row0 + rr;
                int n = wn * 64 + an * 16 + col;
                outb[(size_t)m * HW + n] = acc[am][an][rr];
            }
}

// ---------------------------------------------------------------------------
extern "C" void kernel_launch(void* const* d_in, const int* in_sizes, int n_in,
                              void* d_out, int out_size, void* d_ws, size_t ws_size,
                              hipStream_t stream) {
    const float* x      = (const float*)d_in[0];
    const float* alphas = (const float*)d_in[1];
    const float* angles = (const float*)d_in[2];
    const float* weight = (const float*)d_in[3];
    float* out = (float*)d_out;

    // ws: rw 18.87 MB | xt 35.68 MB | rm 20.7 KB
    ushort_t* rw = (ushort_t*)d_ws;
    ushort_t* xt = (ushort_t*)((char*)d_ws + (size_t)B_ * COUT * K_TOT * 2);
    float*    rm = (float*)((char*)d_ws + (size_t)B_ * COUT * K_TOT * 2
                                        + (size_t)64 * PLANE * 64 * 2);

    rot_mats_kernel<<<1, 64, 0, stream>>>(alphas, angles, rm);
    build_rw_kernel<<<dim3(COUT * CIN / 256, B_), 256, 0, stream>>>(weight, rm, rw);
    halo_zero_kernel<<<64, 256, 0, stream>>>(xt);
    nhwc_kernel<<<dim3(64, 8, B_), 256, 0, stream>>>(x, xt);
    conv_kernel<<<256, 512, 0, stream>>>(xt, rw, out);
}

// Round 12
// 122.793 us; speedup vs baseline: 1.7817x; 1.7817x over previous
//
#include <hip/hip_runtime.h>
#include <hip/hip_bf16.h>

#define B_    16
#define N_    4
#define COUT  256
#define CIN   256
#define H_    64
#define W_    64
#define K_TOT (CIN * 9)    // 2304, k = p*256 + cin (p-major)
#define HW    (H_ * W_)    // 4096
#define NKT   72           // K-tiles of 32
#define PAD   66
#define PLANE (PAD * PAD)  // 4356 padded pixels per (b, cb4) plane

typedef __attribute__((ext_vector_type(8))) short short8;
typedef __attribute__((ext_vector_type(4))) float f32x4;
typedef unsigned short ushort_t;

static __device__ __forceinline__ ushort_t f2bf(float f) {
    __hip_bfloat16 h = __float2bfloat16(f);
    return *reinterpret_cast<ushort_t*>(&h);
}

typedef __attribute__((address_space(3))) unsigned int lds_u32;
typedef __attribute__((address_space(1))) const unsigned int glb_u32;
static __device__ __forceinline__ void gl_lds16(const ushort_t* g, ushort_t* l) {
    __builtin_amdgcn_global_load_lds((glb_u32*)g, (lds_u32*)l, 16, 0, 0);
}

#define BARRIER() asm volatile("s_barrier" ::: "memory")
#define VMCNTN(N) asm volatile("s_waitcnt vmcnt(" #N ")" ::: "memory")

// ---------------------------------------------------------------------------
// Kernel 1: 9x9 rotation matrices, scaled by alpha.  rm[b*N_+n][9][9] floats.
// ---------------------------------------------------------------------------
__global__ void rot_mats_kernel(const float* __restrict__ alphas,
                                const float* __restrict__ angles,
                                float* __restrict__ rm) {
    int i = threadIdx.x;
    if (i >= B_ * N_) return;
    float th = angles[i], al = alphas[i];
    float xc = cosf(th), ys = sinf(th);
    float a = xc - ys, b = xc * ys, c = xc + ys;
    float r[81];
#pragma unroll
    for (int j = 0; j < 81; ++j) r[j] = 0.f;
    if (th >= 0.f) {
        r[0] = a;          r[1] = 1.f - a;
        r[10] = xc - b;    r[11] = b;        r[13] = 1.f - c + b; r[14] = ys - b;
        r[20] = a;         r[23] = 1.f - a;
        r[27] = b;         r[28] = ys - b;   r[30] = xc - b;      r[31] = 1.f - c + b;
        r[40] = 1.f;
        r[49] = 1.f - c + b; r[50] = xc - b; r[52] = ys - b;      r[53] = b;
        r[57] = 1.f - a;   r[60] = a;
        r[66] = ys - b;    r[67] = 1.f - c + b; r[69] = b;        r[70] = xc - b;
        r[79] = 1.f - a;   r[80] = a;
    } else {
        r[0] = c;          r[3] = 1.f - c;
        r[9] = -b;         r[10] = xc + b;   r[12] = b - ys;      r[13] = 1.f - a - b;
        r[19] = 1.f - c;   r[20] = c;
        r[30] = xc + b;    r[31] = 1.f - a - b; r[33] = -b;       r[34] = b - ys;
        r[40] = 1.f;
        r[46] = b - ys;    r[47] = -b;       r[49] = 1.f - a - b; r[50] = xc + b;
        r[60] = c;         r[61] = 1.f - c;
        r[67] = 1.f - a - b; r[68] = b - ys; r[70] = xc + b;      r[71] = -b;
        r[77] = 1.f - c;   r[80] = c;
    }
#pragma unroll
    for (int j = 0; j < 81; ++j) rm[i * 81 + j] = r[j] * al;
}

// ---------------------------------------------------------------------------
// Kernel 2: rw[b][cout][p*256 + cin] (bf16, p-major K layout)
// ---------------------------------------------------------------------------
__global__ __launch_bounds__(256)
void build_rw_kernel(const float* __restrict__ weight,
                     const float* __restrict__ rm,
                     ushort_t* __restrict__ rw) {
    __shared__ float rms[N_ * 81];        // 324 floats
    int tid = threadIdx.x;
    int b = blockIdx.y;
    for (int j = tid; j < N_ * 81; j += 256)
        rms[j] = rm[b * N_ * 81 + j];
    __syncthreads();

    int idx = blockIdx.x * 256 + tid;     // cout*256 + cin
    int cout = idx >> 8, cin = idx & 255;

    float wv[N_][9];
#pragma unroll
    for (int n = 0; n < N_; ++n)
#pragma unroll
        for (int q = 0; q < 9; ++q)
            wv[n][q] = weight[(size_t)(n * (COUT * CIN) + idx) * 9 + q];

    ushort_t* dst = rw + (size_t)(b * COUT + cout) * K_TOT + cin;
#pragma unroll
    for (int p = 0; p < 9; ++p) {
        float s = 0.f;
#pragma unroll
        for (int n = 0; n < N_; ++n)
#pragma unroll
            for (int q = 0; q < 9; ++q)
                s += rms[n * 81 + p * 9 + q] * wv[n][q];
        dst[p * 256] = f2bf(s);
    }
}

// ---------------------------------------------------------------------------
// Kernel 2a: zero the halo ring of each padded plane (260 px x 64 cin).
// grid: 64 planes (b*4 + cb4).
// ---------------------------------------------------------------------------
__global__ __launch_bounds__(256)
void halo_zero_kernel(ushort_t* __restrict__ xt) {
    ushort_t* base = xt + (size_t)blockIdx.x * PLANE * 64;
    int t = threadIdx.x;
    for (int i = t; i < 260; i += 256) {
        int py, px;
        if (i < 66)       { py = 0;  px = i; }
        else if (i < 132) { py = 65; px = i - 66; }
        else if (i < 196) { py = i - 132 + 1; px = 0; }
        else              { py = i - 196 + 1; px = 65; }
        ushort_t* d = base + (size_t)(py * PAD + px) * 64;
        int4 z = {0, 0, 0, 0};
#pragma unroll
        for (int q = 0; q < 8; ++q) *(int4*)(d + q * 8) = z;
    }
}

// ---------------------------------------------------------------------------
// Kernel 2b: interior repack: x fp32 [b][c][64][64] -> xt bf16
//   [b][cb4(4)][y+1][x+1][64cin].  grid (64 rows, 8 cb32, B_), 256 thr.
// ---------------------------------------------------------------------------
__global__ __launch_bounds__(256)
void nhwc_kernel(const float* __restrict__ x, ushort_t* __restrict__ xt) {
    int y    = blockIdx.x;
    int cb32 = blockIdx.y;
    int b    = blockIdx.z;
    __shared__ ushort_t tileT[64][40];    // [px][ci(32)], 80B rows
    int t = threadIdx.x;

    int ci = t & 31, seg = t >> 5;        // 8 segs x 8 px
    const float* src = x + ((size_t)(b * CIN + cb32 * 32 + ci) * HW + y * 64 + seg * 8);
    float4 f0 = ((const float4*)src)[0];
    float4 f1 = ((const float4*)src)[1];
#pragma unroll
    for (int q = 0; q < 4; ++q) tileT[seg * 8 + q][ci]     = f2bf(((float*)&f0)[q]);
#pragma unroll
    for (int q = 0; q < 4; ++q) tileT[seg * 8 + 4 + q][ci] = f2bf(((float*)&f1)[q]);
    __syncthreads();

    int px = t >> 2, cseg = t & 3;        // 64 px x 4 x 16B
    ushort_t* dst = xt + ((size_t)(b * 4 + (cb32 >> 1)) * PLANE + (y + 1) * PAD + px + 1) * 64
                       + (cb32 & 1) * 32 + cseg * 8;
    *(int4*)dst = *(const int4*)&tileT[px][cseg * 8];
}

// ---------------------------------------------------------------------------
// Kernel 3: 128(M couts) x 256(N px) implicit-GEMM conv, BK=32, RING-3
// counted-vmcnt pipeline (T3+T4), pair-row-packed 128B LDS rows with
// involution c = s^(l&7) (T2, 0-conflict by construction), setprio (T5),
// bijective XCD swizzle (T1).
// 512 thr = 8 waves (2M x 4N), wave tile 64x64, acc[4][4] (64 VGPR).
// Per K-tile: {stage kt+2 (3 loads) | ds_read af/bf | 16 MFMA | vmcnt(3) | bar}
// LDS = 3 x (8KB A + 16KB B) = 72 KB -> 2 blocks/CU co-resident (grid 512,
// one residency pass).
// ---------------------------------------------------------------------------
__global__ __launch_bounds__(512, 4)
void conv_kernel(const ushort_t* __restrict__ xt,
                 const ushort_t* __restrict__ rw,
                 float* __restrict__ out) {
    int bid0 = blockIdx.x;
    int bid = (bid0 & 7) * 64 + (bid0 >> 3);   // 512 = 8*64: bijective
    int ch    = bid & 1;         // cout half
    int ptile = (bid >> 1) & 15; // pixel tile: 4 image rows
    int b     = bid >> 5;
    int m0 = ch * 128;
    int y0 = ptile * 4;
    int tid = threadIdx.x;
    int lane = tid & 63, wid = tid >> 6;
    int wm = wid >> 2, wn = wid & 3;
    int rA = lane & 15, kseg = lane >> 4;

    __shared__ __align__(16) ushort_t As[3][4096];   // 3 x 8 KB  (64 l x 64)
    __shared__ __align__(16) ushort_t Bs[3][8192];   // 3 x 16 KB (128 l x 64)
    ushort_t* AsB = &As[0][0];
    ushort_t* BsB = &Bs[0][0];

    f32x4 acc[4][4] = {};

    const ushort_t* rwb = rw + (size_t)(b * COUT + m0) * K_TOT;
    const ushort_t* xtb = xt + ((size_t)b * 4 * PLANE + (size_t)y0 * PAD) * 64;

    // ---- staging geometry (pair-row packing) ----
    // A: 512 units; u=tid: l=u>>3, s=u&7, c=s^(l&7); row=2l+(c>>2), chunk=c&3
    {
    }
    int la = tid >> 3, sa = tid & 7;
    int ca = sa ^ (la & 7);
    const ushort_t* aSrc = rwb + (size_t)(2 * la + (ca >> 2)) * K_TOT + (ca & 3) * 8;
    const int aDst = tid * 8;
    // B: 1024 units; u = i*512+tid
    int bsrc[2], bDst[2];
#pragma unroll
    for (int i = 0; i < 2; ++i) {
        int u = i * 512 + tid;
        int lb = u >> 3, sb = u & 7;
        int cb = sb ^ (lb & 7);
        int px = 2 * lb + (cb >> 2);               // 0..255
        bsrc[i] = ((px >> 6) * PAD + (px & 63)) * 64 + (cb & 3) * 8;
        bDst[i] = u * 8;
    }
    // ---- read geometry: slot = (kseg + 4*(r&1)) ^ ((r>>1)&7), lane-constant
    const int slotR = (kseg + 4 * (rA & 1)) ^ ((rA >> 1) & 7);
    const int aRd = (wm * 32 + (rA >> 1)) * 64 + slotR * 8;   // + mi*512
    const int bRd = (wn * 32 + (rA >> 1)) * 64 + slotR * 8;   // + ni*512

#define STAGE(KT, Q)                                                           \
    {                                                                          \
        int p_ = (KT) >> 3, sub_ = (KT) & 7;                                   \
        int ph_ = p_ / 3, pw_ = p_ - 3 * ph_;                                  \
        gl_lds16(aSrc + p_ * 256 + sub_ * 32, AsB + (Q) * 4096 + aDst);        \
        const ushort_t* sb_ = xtb + (size_t)((sub_ >> 1) * PLANE + ph_ * PAD + pw_) * 64 \
                              + (sub_ & 1) * 32;                               \
        gl_lds16(sb_ + bsrc[0], BsB + (Q) * 8192 + bDst[0]);                   \
        gl_lds16(sb_ + bsrc[1], BsB + (Q) * 8192 + bDst[1]);                   \
    }

    // ---- prologue: tiles 0,1 into buffers 0,1 ----
    STAGE(0, 0);
    STAGE(1, 1);
    VMCNTN(3);               // tile 0 landed; tile 1's 3 loads in flight
    BARRIER();

    int qc = 0;
    for (int kt = 0; kt < NKT; ++kt) {
        int qs = qc + 2; if (qs >= 3) qs -= 3;     // buffer of kt+2
        if (kt + 2 < NKT) STAGE(kt + 2, qs);

        short8 af[4], bf[4];
#pragma unroll
        for (int mi = 0; mi < 4; ++mi)
            af[mi] = *(const short8*)(AsB + qc * 4096 + aRd + mi * 512);
#pragma unroll
        for (int ni = 0; ni < 4; ++ni)
            bf[ni] = *(const short8*)(BsB + qc * 8192 + bRd + ni * 512);

        __builtin_amdgcn_s_setprio(1);
#pragma unroll
        for (int mi = 0; mi < 4; ++mi)
#pragma unroll
            for (int ni = 0; ni < 4; ++ni)
                acc[mi][ni] = __builtin_amdgcn_mfma_f32_16x16x32_bf16(
                    af[mi], bf[ni], acc[mi][ni], 0, 0, 0);
        __builtin_amdgcn_s_setprio(0);

        if (kt <= NKT - 3)      { VMCNTN(3); }     // kt+1 landed; kt+2 in flight
        else if (kt == NKT - 2) { VMCNTN(0); }     // final tile landed
        BARRIER();
        qc = (qc == 2) ? 0 : qc + 1;
    }
#undef STAGE

    // ---- epilogue: D[row=(lane>>4)*4+rr][col=lane&15] ----
    int row0 = (lane >> 4) * 4;
    int col  = lane & 15;
    float* outb = out + ((size_t)(b * COUT) + m0) * HW + ptile * 256;
#pragma unroll
    for (int mi = 0; mi < 4; ++mi)
#pragma unroll
        for (int ni = 0; ni < 4; ++ni)
#pragma unroll
            for (int rr = 0; rr < 4; ++rr) {
                int m = wm * 64 + mi * 16 + row0 + rr;
                int n = wn * 64 + ni * 16 + col;
                outb[(size_t)m * HW + n] = acc[mi][ni][rr];
            }
}

// ---------------------------------------------------------------------------
extern "C" void kernel_launch(void* const* d_in, const int* in_sizes, int n_in,
                              void* d_out, int out_size, void* d_ws, size_t ws_size,
                              hipStream_t stream) {
    const float* x      = (const float*)d_in[0];
    const float* alphas = (const float*)d_in[1];
    const float* angles = (const float*)d_in[2];
    const float* weight = (const float*)d_in[3];
    float* out = (float*)d_out;

    // ws: rw 18.87 MB | xt 35.68 MB | rm 20.7 KB
    ushort_t* rw = (ushort_t*)d_ws;
    ushort_t* xt = (ushort_t*)((char*)d_ws + (size_t)B_ * COUT * K_TOT * 2);
    float*    rm = (float*)((char*)d_ws + (size_t)B_ * COUT * K_TOT * 2
                                        + (size_t)64 * PLANE * 64 * 2);

    rot_mats_kernel<<<1, 64, 0, stream>>>(alphas, angles, rm);
    build_rw_kernel<<<dim3(COUT * CIN / 256, B_), 256, 0, stream>>>(weight, rm, rw);
    halo_zero_kernel<<<64, 256, 0, stream>>>(xt);
    nhwc_kernel<<<dim3(64, 8, B_), 256, 0, stream>>>(x, xt);
    conv_kernel<<<512, 512, 0, stream>>>(xt, rw, out);
}

// Round 13
// 121.520 us; speedup vs baseline: 1.8004x; 1.0105x over previous
//
#include <hip/hip_runtime.h>
#include <hip/hip_bf16.h>

#define B_    16
#define N_    4
#define COUT  256
#define CIN   256
#define H_    64
#define W_    64
#define K_TOT (CIN * 9)    // 2304, k = p*256 + cin (p-major)
#define HW    (H_ * W_)    // 4096
#define NKT   72           // K-tiles of 32
#define PAD   66
#define PLANE (PAD * PAD)  // 4356 padded pixels per (b, cb4) plane

typedef __attribute__((ext_vector_type(8))) short short8;
typedef __attribute__((ext_vector_type(4))) float f32x4;
typedef unsigned short ushort_t;

static __device__ __forceinline__ ushort_t f2bf(float f) {
    __hip_bfloat16 h = __float2bfloat16(f);
    return *reinterpret_cast<ushort_t*>(&h);
}

typedef __attribute__((address_space(3))) unsigned int lds_u32;
typedef __attribute__((address_space(1))) const unsigned int glb_u32;
static __device__ __forceinline__ void gl_lds16(const ushort_t* g, ushort_t* l) {
    __builtin_amdgcn_global_load_lds((glb_u32*)g, (lds_u32*)l, 16, 0, 0);
}

#define BARRIER() asm volatile("s_barrier" ::: "memory")
#define VMCNTN(N) asm volatile("s_waitcnt vmcnt(" #N ")" ::: "memory")

// ---------------------------------------------------------------------------
// Kernel 1: 9x9 rotation matrices, scaled by alpha.  rm[b*N_+n][9][9] floats.
// ---------------------------------------------------------------------------
__global__ void rot_mats_kernel(const float* __restrict__ alphas,
                                const float* __restrict__ angles,
                                float* __restrict__ rm) {
    int i = threadIdx.x;
    if (i >= B_ * N_) return;
    float th = angles[i], al = alphas[i];
    float xc = cosf(th), ys = sinf(th);
    float a = xc - ys, b = xc * ys, c = xc + ys;
    float r[81];
#pragma unroll
    for (int j = 0; j < 81; ++j) r[j] = 0.f;
    if (th >= 0.f) {
        r[0] = a;          r[1] = 1.f - a;
        r[10] = xc - b;    r[11] = b;        r[13] = 1.f - c + b; r[14] = ys - b;
        r[20] = a;         r[23] = 1.f - a;
        r[27] = b;         r[28] = ys - b;   r[30] = xc - b;      r[31] = 1.f - c + b;
        r[40] = 1.f;
        r[49] = 1.f - c + b; r[50] = xc - b; r[52] = ys - b;      r[53] = b;
        r[57] = 1.f - a;   r[60] = a;
        r[66] = ys - b;    r[67] = 1.f - c + b; r[69] = b;        r[70] = xc - b;
        r[79] = 1.f - a;   r[80] = a;
    } else {
        r[0] = c;          r[3] = 1.f - c;
        r[9] = -b;         r[10] = xc + b;   r[12] = b - ys;      r[13] = 1.f - a - b;
        r[19] = 1.f - c;   r[20] = c;
        r[30] = xc + b;    r[31] = 1.f - a - b; r[33] = -b;       r[34] = b - ys;
        r[40] = 1.f;
        r[46] = b - ys;    r[47] = -b;       r[49] = 1.f - a - b; r[50] = xc + b;
        r[60] = c;         r[61] = 1.f - c;
        r[67] = 1.f - a - b; r[68] = b - ys; r[70] = xc + b;      r[71] = -b;
        r[77] = 1.f - c;   r[80] = c;
    }
#pragma unroll
    for (int j = 0; j < 81; ++j) rm[i * 81 + j] = r[j] * al;
}

// ---------------------------------------------------------------------------
// Kernel 2: rw[b][cout][p*256 + cin] (bf16, p-major K layout)
// ---------------------------------------------------------------------------
__global__ __launch_bounds__(256)
void build_rw_kernel(const float* __restrict__ weight,
                     const float* __restrict__ rm,
                     ushort_t* __restrict__ rw) {
    __shared__ float rms[N_ * 81];        // 324 floats
    int tid = threadIdx.x;
    int b = blockIdx.y;
    for (int j = tid; j < N_ * 81; j += 256)
        rms[j] = rm[b * N_ * 81 + j];
    __syncthreads();

    int idx = blockIdx.x * 256 + tid;     // cout*256 + cin
    int cout = idx >> 8, cin = idx & 255;

    float wv[N_][9];
#pragma unroll
    for (int n = 0; n < N_; ++n)
#pragma unroll
        for (int q = 0; q < 9; ++q)
            wv[n][q] = weight[(size_t)(n * (COUT * CIN) + idx) * 9 + q];

    ushort_t* dst = rw + (size_t)(b * COUT + cout) * K_TOT + cin;
#pragma unroll
    for (int p = 0; p < 9; ++p) {
        float s = 0.f;
#pragma unroll
        for (int n = 0; n < N_; ++n)
#pragma unroll
            for (int q = 0; q < 9; ++q)
                s += rms[n * 81 + p * 9 + q] * wv[n][q];
        dst[p * 256] = f2bf(s);
    }
}

// ---------------------------------------------------------------------------
// Kernel 2a: zero the halo ring of each padded plane (260 px x 64 cin).
// grid: 64 planes (b*4 + cb4).
// ---------------------------------------------------------------------------
__global__ __launch_bounds__(256)
void halo_zero_kernel(ushort_t* __restrict__ xt) {
    ushort_t* base = xt + (size_t)blockIdx.x * PLANE * 64;
    int t = threadIdx.x;
    for (int i = t; i < 260; i += 256) {
        int py, px;
        if (i < 66)       { py = 0;  px = i; }
        else if (i < 132) { py = 65; px = i - 66; }
        else if (i < 196) { py = i - 132 + 1; px = 0; }
        else              { py = i - 196 + 1; px = 65; }
        ushort_t* d = base + (size_t)(py * PAD + px) * 64;
        int4 z = {0, 0, 0, 0};
#pragma unroll
        for (int q = 0; q < 8; ++q) *(int4*)(d + q * 8) = z;
    }
}

// ---------------------------------------------------------------------------
// Kernel 2b: interior repack: x fp32 [b][c][64][64] -> xt bf16
//   [b][cb4(4)][y+1][x+1][64cin].  grid (64 rows, 8 cb32, B_), 256 thr.
// ---------------------------------------------------------------------------
__global__ __launch_bounds__(256)
void nhwc_kernel(const float* __restrict__ x, ushort_t* __restrict__ xt) {
    int y    = blockIdx.x;
    int cb32 = blockIdx.y;
    int b    = blockIdx.z;
    __shared__ ushort_t tileT[64][40];    // [px][ci(32)], 80B rows
    int t = threadIdx.x;

    int ci = t & 31, seg = t >> 5;        // 8 segs x 8 px
    const float* src = x + ((size_t)(b * CIN + cb32 * 32 + ci) * HW + y * 64 + seg * 8);
    float4 f0 = ((const float4*)src)[0];
    float4 f1 = ((const float4*)src)[1];
#pragma unroll
    for (int q = 0; q < 4; ++q) tileT[seg * 8 + q][ci]     = f2bf(((float*)&f0)[q]);
#pragma unroll
    for (int q = 0; q < 4; ++q) tileT[seg * 8 + 4 + q][ci] = f2bf(((float*)&f1)[q]);
    __syncthreads();

    int px = t >> 2, cseg = t & 3;        // 64 px x 4 x 16B
    ushort_t* dst = xt + ((size_t)(b * 4 + (cb32 >> 1)) * PLANE + (y + 1) * PAD + px + 1) * 64
                       + (cb32 & 1) * 32 + cseg * 8;
    *(int4*)dst = *(const int4*)&tileT[px][cseg * 8];
}

// ---------------------------------------------------------------------------
// Kernel 3: 256(M) x 256(N) implicit-GEMM conv, BK=32, RING-3 counted-vmcnt
// (T3+T4) with TWO phases per K-tile, pair-row 128B LDS rows + involution
// swizzle (T2, 0-conflict proven in R12), setprio (T5), XCD swizzle (T1).
// 512 thr = 8 waves (2M x 4N), wave tile 128x64, acc[8][4] (0.375 reads/MFMA).
// Per K-tile: ph1{read af[0..3]+bf, stageA kt+2, bar, 16 MFMA, bar}
//             ph2{read af[4..7],    stageB kt+2, bar, 16 MFMA, vmcnt(4), bar}
// LDS = 3 x (16KB A + 16KB B) = 96 KB (1 block/CU, grid 256 = one pass).
// ---------------------------------------------------------------------------
__global__ __launch_bounds__(512, 2)
void conv_kernel(const ushort_t* __restrict__ xt,
                 const ushort_t* __restrict__ rw,
                 float* __restrict__ out) {
    int bid0 = blockIdx.x;
    int bid = (bid0 & 7) * 32 + (bid0 >> 3);   // 256 = 8*32: bijective
    int b     = bid >> 4;
    int ptile = bid & 15;       // pixel tile: 4 image rows
    int y0 = ptile * 4;
    int tid = threadIdx.x;
    int lane = tid & 63, wid = tid >> 6;
    int wm = wid >> 2, wn = wid & 3;
    int rA = lane & 15, kseg = lane >> 4;

    __shared__ __align__(16) ushort_t As[3][8192];   // 3 x 16 KB (256 rows x 32k)
    __shared__ __align__(16) ushort_t Bs[3][8192];   // 3 x 16 KB (256 px x 32k)
    ushort_t* AsB = &As[0][0];
    ushort_t* BsB = &Bs[0][0];

    f32x4 acc[8][4] = {};

    const ushort_t* rwb = rw + (size_t)b * COUT * K_TOT;
    const ushort_t* xtb = xt + ((size_t)b * 4 * PLANE + (size_t)y0 * PAD) * 64;

    // ---- staging geometry (pair-row packing, R12-proven) ----
    // unit u (0..1023): l=u>>3, s=u&7, c=s^(l&7); row=2l+(c>>2), chunk=c&3
    int asrc[2], bsrc[2], uDst[2];
#pragma unroll
    for (int i = 0; i < 2; ++i) {
        int u = i * 512 + tid;
        int l = u >> 3, s = u & 7;
        int c = s ^ (l & 7);
        int row = 2 * l + (c >> 2);                // 0..255
        asrc[i] = row * K_TOT + (c & 3) * 8;
        bsrc[i] = ((row >> 6) * PAD + (row & 63)) * 64 + (c & 3) * 8;
        uDst[i] = u * 8;
    }
    // ---- read geometry (lane-constant slot, R12-proven) ----
    const int slotR = (kseg + 4 * (rA & 1)) ^ ((rA >> 1) & 7);
    const int aRd = (wm * 64 + (rA >> 1)) * 64 + slotR * 8;   // + mi*512
    const int bRd = (wn * 32 + (rA >> 1)) * 64 + slotR * 8;   // + ni*512

#define STAGE_A(KT, Q)                                                         \
    {                                                                          \
        int p_ = (KT) >> 3, sub_ = (KT) & 7;                                   \
        int ako = p_ * 256 + sub_ * 32;                                        \
        gl_lds16(rwb + asrc[0] + ako, AsB + (Q) * 8192 + uDst[0]);             \
        gl_lds16(rwb + asrc[1] + ako, AsB + (Q) * 8192 + uDst[1]);             \
    }

#define STAGE_B(KT, Q)                                                         \
    {                                                                          \
        int p_ = (KT) >> 3, sub_ = (KT) & 7;                                   \
        int ph_ = p_ / 3, pw_ = p_ - 3 * ph_;                                  \
        const ushort_t* sb_ = xtb + (size_t)((sub_ >> 1) * PLANE + ph_ * PAD + pw_) * 64 \
                              + (sub_ & 1) * 32;                               \
        gl_lds16(sb_ + bsrc[0], BsB + (Q) * 8192 + uDst[0]);                   \
        gl_lds16(sb_ + bsrc[1], BsB + (Q) * 8192 + uDst[1]);                   \
    }

#define DO_MFMA(MH)                                                            \
    __builtin_amdgcn_s_setprio(1);                                             \
    _Pragma("unroll")                                                          \
    for (int mi = 0; mi < 4; ++mi)                                             \
        _Pragma("unroll")                                                      \
        for (int ni = 0; ni < 4; ++ni)                                         \
            acc[(MH) * 4 + mi][ni] = __builtin_amdgcn_mfma_f32_16x16x32_bf16(  \
                af[mi], bf[ni], acc[(MH) * 4 + mi][ni], 0, 0, 0);              \
    __builtin_amdgcn_s_setprio(0);

    // ---- prologue: tiles 0,1 into buffers 0,1 ----
    STAGE_A(0, 0); STAGE_B(0, 0);
    STAGE_A(1, 1); STAGE_B(1, 1);
    VMCNTN(4);               // tile 0 landed; tile 1's 4 loads in flight
    BARRIER();

    short8 af[4], bf[4];
    int qc = 0;
    for (int kt = 0; kt < NKT; ++kt) {
        int qs = qc + 2; if (qs >= 3) qs -= 3;     // buffer of kt+2
        bool more = (kt + 2 < NKT);
        // ---- phase 1: m-half 0; stage A of kt+2 ----
#pragma unroll
        for (int mi = 0; mi < 4; ++mi)
            af[mi] = *(const short8*)(AsB + qc * 8192 + aRd + mi * 512);
#pragma unroll
        for (int ni = 0; ni < 4; ++ni)
            bf[ni] = *(const short8*)(BsB + qc * 8192 + bRd + ni * 512);
        if (more) STAGE_A(kt + 2, qs);
        BARRIER();
        DO_MFMA(0);
        BARRIER();
        // ---- phase 2: m-half 1 (bf reused); stage B of kt+2 ----
#pragma unroll
        for (int mi = 0; mi < 4; ++mi)
            af[mi] = *(const short8*)(AsB + qc * 8192 + aRd + (mi + 4) * 512);
        if (more) STAGE_B(kt + 2, qs);
        BARRIER();
        DO_MFMA(1);
        if (kt <= NKT - 3)      { VMCNTN(4); }     // kt+1 landed; kt+2 in flight
        else if (kt == NKT - 2) { VMCNTN(0); }
        BARRIER();
        qc = (qc == 2) ? 0 : qc + 1;
    }
#undef STAGE_A
#undef STAGE_B
#undef DO_MFMA

    // ---- epilogue: D[row=(lane>>4)*4+rr][col=lane&15] ----
    int row0 = (lane >> 4) * 4;
    int col  = lane & 15;
    float* outb = out + (size_t)b * COUT * HW + ptile * 256;
#pragma unroll
    for (int am = 0; am < 8; ++am)
#pragma unroll
        for (int an = 0; an < 4; ++an)
#pragma unroll
            for (int rr = 0; rr < 4; ++rr) {
                int m = wm * 128 + am * 16 + row0 + rr;
                int n = wn * 64 + an * 16 + col;
                outb[(size_t)m * HW + n] = acc[am][an][rr];
            }
}

// ---------------------------------------------------------------------------
extern "C" void kernel_launch(void* const* d_in, const int* in_sizes, int n_in,
                              void* d_out, int out_size, void* d_ws, size_t ws_size,
                              hipStream_t stream) {
    const float* x      = (const float*)d_in[0];
    const float* alphas = (const float*)d_in[1];
    const float* angles = (const float*)d_in[2];
    const float* weight = (const float*)d_in[3];
    float* out = (float*)d_out;

    // ws: rw 18.87 MB | xt 35.68 MB | rm 20.7 KB
    ushort_t* rw = (ushort_t*)d_ws;
    ushort_t* xt = (ushort_t*)((char*)d_ws + (size_t)B_ * COUT * K_TOT * 2);
    float*    rm = (float*)((char*)d_ws + (size_t)B_ * COUT * K_TOT * 2
                                        + (size_t)64 * PLANE * 64 * 2);

    rot_mats_kernel<<<1, 64, 0, stream>>>(alphas, angles, rm);
    build_rw_kernel<<<dim3(COUT * CIN / 256, B_), 256, 0, stream>>>(weight, rm, rw);
    halo_zero_kernel<<<64, 256, 0, stream>>>(xt);
    nhwc_kernel<<<dim3(64, 8, B_), 256, 0, stream>>>(x, xt);
    conv_kernel<<<256, 512, 0, stream>>>(xt, rw, out);
}

// Round 14
// 117.108 us; speedup vs baseline: 1.8682x; 1.0377x over previous
//
#include <hip/hip_runtime.h>
#include <hip/hip_bf16.h>

#define B_    16
#define N_    4
#define COUT  256
#define CIN   256
#define H_    64
#define W_    64
#define K_TOT (CIN * 9)    // 2304, k = p*256 + cin (p-major)
#define HW    (H_ * W_)    // 4096
#define NKT   72           // K-tiles of 32
#define PAD   66
#define PLANE (PAD * PAD)  // 4356 padded pixels per (b, cb4) plane

typedef __attribute__((ext_vector_type(8))) short short8;
typedef __attribute__((ext_vector_type(4))) float f32x4;
typedef unsigned short ushort_t;

static __device__ __forceinline__ ushort_t f2bf(float f) {
    __hip_bfloat16 h = __float2bfloat16(f);
    return *reinterpret_cast<ushort_t*>(&h);
}

typedef __attribute__((address_space(3))) unsigned int lds_u32;
typedef __attribute__((address_space(1))) const unsigned int glb_u32;
static __device__ __forceinline__ void gl_lds16(const ushort_t* g, ushort_t* l) {
    __builtin_amdgcn_global_load_lds((glb_u32*)g, (lds_u32*)l, 16, 0, 0);
}

#define BARRIER() asm volatile("s_barrier" ::: "memory")
#define VMCNTN(N) asm volatile("s_waitcnt vmcnt(" #N ")" ::: "memory")

// ---------------------------------------------------------------------------
// Kernel 1: 9x9 rotation matrices, scaled by alpha.  rm[b*N_+n][9][9] floats.
// ---------------------------------------------------------------------------
__global__ void rot_mats_kernel(const float* __restrict__ alphas,
                                const float* __restrict__ angles,
                                float* __restrict__ rm) {
    int i = threadIdx.x;
    if (i >= B_ * N_) return;
    float th = angles[i], al = alphas[i];
    float xc = cosf(th), ys = sinf(th);
    float a = xc - ys, b = xc * ys, c = xc + ys;
    float r[81];
#pragma unroll
    for (int j = 0; j < 81; ++j) r[j] = 0.f;
    if (th >= 0.f) {
        r[0] = a;          r[1] = 1.f - a;
        r[10] = xc - b;    r[11] = b;        r[13] = 1.f - c + b; r[14] = ys - b;
        r[20] = a;         r[23] = 1.f - a;
        r[27] = b;         r[28] = ys - b;   r[30] = xc - b;      r[31] = 1.f - c + b;
        r[40] = 1.f;
        r[49] = 1.f - c + b; r[50] = xc - b; r[52] = ys - b;      r[53] = b;
        r[57] = 1.f - a;   r[60] = a;
        r[66] = ys - b;    r[67] = 1.f - c + b; r[69] = b;        r[70] = xc - b;
        r[79] = 1.f - a;   r[80] = a;
    } else {
        r[0] = c;          r[3] = 1.f - c;
        r[9] = -b;         r[10] = xc + b;   r[12] = b - ys;      r[13] = 1.f - a - b;
        r[19] = 1.f - c;   r[20] = c;
        r[30] = xc + b;    r[31] = 1.f - a - b; r[33] = -b;       r[34] = b - ys;
        r[40] = 1.f;
        r[46] = b - ys;    r[47] = -b;       r[49] = 1.f - a - b; r[50] = xc + b;
        r[60] = c;         r[61] = 1.f - c;
        r[67] = 1.f - a - b; r[68] = b - ys; r[70] = xc + b;      r[71] = -b;
        r[77] = 1.f - c;   r[80] = c;
    }
#pragma unroll
    for (int j = 0; j < 81; ++j) rm[i * 81 + j] = r[j] * al;
}

// ---------------------------------------------------------------------------
// Kernel 2: rw[b][cout][p*256 + cin] (bf16, p-major K layout)
// ---------------------------------------------------------------------------
__global__ __launch_bounds__(256)
void build_rw_kernel(const float* __restrict__ weight,
                     const float* __restrict__ rm,
                     ushort_t* __restrict__ rw) {
    __shared__ float rms[N_ * 81];        // 324 floats
    int tid = threadIdx.x;
    int b = blockIdx.y;
    for (int j = tid; j < N_ * 81; j += 256)
        rms[j] = rm[b * N_ * 81 + j];
    __syncthreads();

    int idx = blockIdx.x * 256 + tid;     // cout*256 + cin
    int cout = idx >> 8, cin = idx & 255;

    float wv[N_][9];
#pragma unroll
    for (int n = 0; n < N_; ++n)
#pragma unroll
        for (int q = 0; q < 9; ++q)
            wv[n][q] = weight[(size_t)(n * (COUT * CIN) + idx) * 9 + q];

    ushort_t* dst = rw + (size_t)(b * COUT + cout) * K_TOT + cin;
#pragma unroll
    for (int p = 0; p < 9; ++p) {
        float s = 0.f;
#pragma unroll
        for (int n = 0; n < N_; ++n)
#pragma unroll
            for (int q = 0; q < 9; ++q)
                s += rms[n * 81 + p * 9 + q] * wv[n][q];
        dst[p * 256] = f2bf(s);
    }
}

// ---------------------------------------------------------------------------
// Kernel 2a: zero the halo ring of each padded plane (260 px x 64 cin).
// grid: 64 planes (b*4 + cb4).
// ---------------------------------------------------------------------------
__global__ __launch_bounds__(256)
void halo_zero_kernel(ushort_t* __restrict__ xt) {
    ushort_t* base = xt + (size_t)blockIdx.x * PLANE * 64;
    int t = threadIdx.x;
    for (int i = t; i < 260; i += 256) {
        int py, px;
        if (i < 66)       { py = 0;  px = i; }
        else if (i < 132) { py = 65; px = i - 66; }
        else if (i < 196) { py = i - 132 + 1; px = 0; }
        else              { py = i - 196 + 1; px = 65; }
        ushort_t* d = base + (size_t)(py * PAD + px) * 64;
        int4 z = {0, 0, 0, 0};
#pragma unroll
        for (int q = 0; q < 8; ++q) *(int4*)(d + q * 8) = z;
    }
}

// ---------------------------------------------------------------------------
// Kernel 2b: interior repack: x fp32 [b][c][64][64] -> xt bf16
//   [b][cb4(4)][y+1][x+1][64cin].  grid (64 rows, 8 cb32, B_), 256 thr.
// ---------------------------------------------------------------------------
__global__ __launch_bounds__(256)
void nhwc_kernel(const float* __restrict__ x, ushort_t* __restrict__ xt) {
    int y    = blockIdx.x;
    int cb32 = blockIdx.y;
    int b    = blockIdx.z;
    __shared__ ushort_t tileT[64][40];    // [px][ci(32)], 80B rows
    int t = threadIdx.x;

    int ci = t & 31, seg = t >> 5;        // 8 segs x 8 px
    const float* src = x + ((size_t)(b * CIN + cb32 * 32 + ci) * HW + y * 64 + seg * 8);
    float4 f0 = ((const float4*)src)[0];
    float4 f1 = ((const float4*)src)[1];
#pragma unroll
    for (int q = 0; q < 4; ++q) tileT[seg * 8 + q][ci]     = f2bf(((float*)&f0)[q]);
#pragma unroll
    for (int q = 0; q < 4; ++q) tileT[seg * 8 + 4 + q][ci] = f2bf(((float*)&f1)[q]);
    __syncthreads();

    int px = t >> 2, cseg = t & 3;        // 64 px x 4 x 16B
    ushort_t* dst = xt + ((size_t)(b * 4 + (cb32 >> 1)) * PLANE + (y + 1) * PAD + px + 1) * 64
                       + (cb32 & 1) * 32 + cseg * 8;
    *(int4*)dst = *(const int4*)&tileT[px][cseg * 8];
}

// ---------------------------------------------------------------------------
// Kernel 3: 256x256 implicit-GEMM conv, BK=32, ring-3 LDS + CROSS-TILE
// REGISTER FRAGMENT PREFETCH: during tile kt, ds_read frags of kt+1 (buffer
// sealed at end of kt-1) into a second reg set while MFMAs of kt run on the
// first set -> LDS pipe overlaps MFMA pipe within each wave.
// Pair-row 128B LDS rows + involution swizzle (0-conflict, R12/R13-proven),
// setprio, bijective XCD swizzle. 512 thr = 8 waves (2Mx4N), wave 128x64,
// acc[8][4]. Per tile: {reads(kt+1) | stage(kt+2) | 32 MFMA | vmcnt(0) | bar}.
// LDS = 3 x (16KB A + 16KB B) = 96 KB, 1 block/CU, grid 256 = one pass.
// ---------------------------------------------------------------------------
__global__ __launch_bounds__(512, 1)
void conv_kernel(const ushort_t* __restrict__ xt,
                 const ushort_t* __restrict__ rw,
                 float* __restrict__ out) {
    int bid0 = blockIdx.x;
    int bid = (bid0 & 7) * 32 + (bid0 >> 3);   // 256 = 8*32: bijective
    int b     = bid >> 4;
    int ptile = bid & 15;       // pixel tile: 4 image rows
    int y0 = ptile * 4;
    int tid = threadIdx.x;
    int lane = tid & 63, wid = tid >> 6;
    int wm = wid >> 2, wn = wid & 3;
    int rA = lane & 15, kseg = lane >> 4;

    __shared__ __align__(16) ushort_t As[3][8192];   // 3 x 16 KB (256 rows x 32k)
    __shared__ __align__(16) ushort_t Bs[3][8192];   // 3 x 16 KB (256 px x 32k)
    ushort_t* AsB = &As[0][0];
    ushort_t* BsB = &Bs[0][0];

    f32x4 acc[8][4] = {};

    const ushort_t* rwb = rw + (size_t)b * COUT * K_TOT;
    const ushort_t* xtb = xt + ((size_t)b * 4 * PLANE + (size_t)y0 * PAD) * 64;

    // ---- staging geometry (pair-row packing, R12-proven) ----
    int asrc[2], bsrc[2], uDst[2];
#pragma unroll
    for (int i = 0; i < 2; ++i) {
        int u = i * 512 + tid;
        int l = u >> 3, s = u & 7;
        int c = s ^ (l & 7);
        int row = 2 * l + (c >> 2);                // 0..255
        asrc[i] = row * K_TOT + (c & 3) * 8;
        bsrc[i] = ((row >> 6) * PAD + (row & 63)) * 64 + (c & 3) * 8;
        uDst[i] = u * 8;
    }
    // ---- read geometry (lane-constant slot, R12-proven) ----
    const int slotR = (kseg + 4 * (rA & 1)) ^ ((rA >> 1) & 7);
    const int aRd = (wm * 64 + (rA >> 1)) * 64 + slotR * 8;   // + mi*512
    const int bRd = (wn * 32 + (rA >> 1)) * 64 + slotR * 8;   // + ni*512

#define STAGE_AB(KT, Q)                                                        \
    {                                                                          \
        int p_ = (KT) >> 3, sub_ = (KT) & 7;                                   \
        int ako = p_ * 256 + sub_ * 32;                                        \
        gl_lds16(rwb + asrc[0] + ako, AsB + (Q) * 8192 + uDst[0]);             \
        gl_lds16(rwb + asrc[1] + ako, AsB + (Q) * 8192 + uDst[1]);             \
        int ph_ = p_ / 3, pw_ = p_ - 3 * ph_;                                  \
        const ushort_t* sb_ = xtb + (size_t)((sub_ >> 1) * PLANE + ph_ * PAD + pw_) * 64 \
                              + (sub_ & 1) * 32;                               \
        gl_lds16(sb_ + bsrc[0], BsB + (Q) * 8192 + uDst[0]);                   \
        gl_lds16(sb_ + bsrc[1], BsB + (Q) * 8192 + uDst[1]);                   \
    }

#define READ_FRAGS(Q, AF, BF)                                                  \
    _Pragma("unroll")                                                          \
    for (int mi = 0; mi < 8; ++mi)                                             \
        AF[mi] = *(const short8*)(AsB + (Q) * 8192 + aRd + mi * 512);          \
    _Pragma("unroll")                                                          \
    for (int ni = 0; ni < 4; ++ni)                                             \
        BF[ni] = *(const short8*)(BsB + (Q) * 8192 + bRd + ni * 512);

    // body: prefetch frags(kt+1) into (AFN,BFN); stage kt+2; MFMA on (AFC,BFC)
#define TILE_BODY(KT, QN, QS, AFC, BFC, AFN, BFN)                              \
    {                                                                          \
        if ((KT) + 1 < NKT) { READ_FRAGS(QN, AFN, BFN); }                      \
        if ((KT) + 2 < NKT) { STAGE_AB((KT) + 2, QS); }                        \
        __builtin_amdgcn_s_setprio(1);                                         \
        _Pragma("unroll")                                                      \
        for (int mi = 0; mi < 8; ++mi)                                         \
            _Pragma("unroll")                                                  \
            for (int ni = 0; ni < 4; ++ni)                                     \
                acc[mi][ni] = __builtin_amdgcn_mfma_f32_16x16x32_bf16(         \
                    AFC[mi], BFC[ni], acc[mi][ni], 0, 0, 0);                   \
        __builtin_amdgcn_s_setprio(0);                                         \
        VMCNTN(0);                                                             \
        BARRIER();                                                             \
    }

    // ---- prologue: stage tiles 0,1 into buffers 0,1; prefetch frags(0) ----
    STAGE_AB(0, 0);
    STAGE_AB(1, 1);
    VMCNTN(0);
    BARRIER();

    short8 afA[8], bfA[4], afB[8], bfB[4];
    READ_FRAGS(0, afA, bfA);

    int qc = 0;                      // buffer of current tile
    for (int kt = 0; kt < NKT; kt += 2) {
        int qn = qc + 1; if (qn >= 3) qn -= 3;
        int qs = qc + 2; if (qs >= 3) qs -= 3;
        TILE_BODY(kt, qn, qs, afA, bfA, afB, bfB);
        // second tile of pair: current buffer qn
        int qn2 = qs;
        int qs2 = qc;
        TILE_BODY(kt + 1, qn2, qs2, afB, bfB, afA, bfA);
        qc = qs;                     // (qc+2)%3 after two tiles
    }
#undef TILE_BODY
#undef READ_FRAGS
#undef STAGE_AB

    // ---- epilogue: D[row=(lane>>4)*4+rr][col=lane&15] ----
    int row0 = (lane >> 4) * 4;
    int col  = lane & 15;
    float* outb = out + (size_t)b * COUT * HW + ptile * 256;
#pragma unroll
    for (int am = 0; am < 8; ++am)
#pragma unroll
        for (int an = 0; an < 4; ++an)
#pragma unroll
            for (int rr = 0; rr < 4; ++rr) {
                int m = wm * 128 + am * 16 + row0 + rr;
                int n = wn * 64 + an * 16 + col;
                outb[(size_t)m * HW + n] = acc[am][an][rr];
            }
}

// ---------------------------------------------------------------------------
extern "C" void kernel_launch(void* const* d_in, const int* in_sizes, int n_in,
                              void* d_out, int out_size, void* d_ws, size_t ws_size,
                              hipStream_t stream) {
    const float* x      = (const float*)d_in[0];
    const float* alphas = (const float*)d_in[1];
    const float* angles = (const float*)d_in[2];
    const float* weight = (const float*)d_in[3];
    float* out = (float*)d_out;

    // ws: rw 18.87 MB | xt 35.68 MB | rm 20.7 KB
    ushort_t* rw = (ushort_t*)d_ws;
    ushort_t* xt = (ushort_t*)((char*)d_ws + (size_t)B_ * COUT * K_TOT * 2);
    float*    rm = (float*)((char*)d_ws + (size_t)B_ * COUT * K_TOT * 2
                                        + (size_t)64 * PLANE * 64 * 2);

    rot_mats_kernel<<<1, 64, 0, stream>>>(alphas, angles, rm);
    build_rw_kernel<<<dim3(COUT * CIN / 256, B_), 256, 0, stream>>>(weight, rm, rw);
    halo_zero_kernel<<<64, 256, 0, stream>>>(xt);
    nhwc_kernel<<<dim3(64, 8, B_), 256, 0, stream>>>(x, xt);
    conv_kernel<<<256, 512, 0, stream>>>(xt, rw, out);
}